// Round 1
// baseline (5527.337 us; speedup 1.0000x reference)
//
#include <hip/hip_runtime.h>

#define ZB 202
#define YX 65536
#define NTOT ((size_t)ZB * YX)

__device__ __forceinline__ constexpr float kMU() { return 0.0009765625f; }  // 2^-10
#define MINV (-32768.0f)
#define MAXV (32767.0f)

// ---------------------------------------------------------------------------
// Phase A: pack tmp4[t][z] = {img[z-3], img[z-2], img[z-1], img[z]} at pixel t.
// LDS tile: 64 z x 64 t (+3 z halo). Reads coalesced along t, writes 1KB
// contiguous float4 runs along z.
// ---------------------------------------------------------------------------
__global__ __launch_bounds__(256) void pack_kernel(const float* __restrict__ img,
                                                   float4* __restrict__ tmp4) {
    __shared__ float lds[67 * 65];  // rows = img z0-3 .. z0+63, pitch 65 (bank-conflict pad)
    const int t0 = blockIdx.x * 64;
    const int z0 = blockIdx.y * 64;
    const int tid = threadIdx.x;
    const int c = tid & 63;
    const int r0 = tid >> 6;

    for (int k = 0; k < 17; ++k) {
        int r = r0 + (k << 2);
        if (r < 67) {
            int gz = z0 - 3 + r;
            float v = 0.0f;
            if (gz >= 0 && gz < ZB) v = img[(size_t)gz * YX + t0 + c];
            lds[r * 65 + c] = v;
        }
    }
    __syncthreads();

    const int zl = tid & 63;
    const int tsub = tid >> 6;
    const int z = z0 + zl;
    if (z >= ZB) return;
    for (int k = 0; k < 16; ++k) {
        int tl = tsub * 16 + k;
        float4 v;
        v.x = lds[(zl + 0) * 65 + tl];  // img[z-3] = n2
        v.y = lds[(zl + 1) * 65 + tl];  // img[z-2] = n1
        v.z = lds[(zl + 2) * 65 + tl];  // img[z-1] = n0
        v.w = lds[(zl + 3) * 65 + tl];  // img[z]   = s
        tmp4[(size_t)(t0 + tl) * ZB + z] = v;
    }
}

// ---------------------------------------------------------------------------
// Phase B: the sequential sign-LMS scan. One lane per band; 4 waves total.
// Explicitly software-pipelined: PF=8 groups of 4 rows in flight (~26KB/wave)
// to cover HBM latency. All recurrence arithmetic uses non-contracted
// round-to-nearest ops to match the reference's float32 trajectory exactly.
// ---------------------------------------------------------------------------
__global__ __launch_bounds__(64) void scan_kernel(const float4* __restrict__ tmp4,
                                                  const float* __restrict__ w0g,
                                                  float* __restrict__ predT) {
    const int z = blockIdx.x * 64 + threadIdx.x;
    if (z >= ZB) return;

    float w0 = w0g[z * 3 + 0];
    float w1 = w0g[z * 3 + 1];
    float w2 = w0g[z * 3 + 2];

    const float4* base = tmp4 + z;
    float* outp = predT + z;

    constexpr int PF = 8;      // groups in flight
    constexpr int U = 4;       // rows per group
    const int NG = YX / U;     // 16384 groups; NG % PF == 0

    float4 buf[PF][U];
#pragma unroll
    for (int s = 0; s < PF; ++s)
#pragma unroll
        for (int j = 0; j < U; ++j)
            buf[s][j] = base[(size_t)(s * U + j) * ZB];

    for (int G = 0; G < NG; G += PF) {
#pragma unroll
        for (int s = 0; s < PF; ++s) {
            const int g = G + s;
#pragma unroll
            for (int j = 0; j < U; ++j) {
                const float4 v = buf[s][j];
                const int t = g * U + j;
                // pred = clip(dot(w, n)) ; left-to-right, no FMA contraction
                float d = __fadd_rn(__fadd_rn(__fmul_rn(w0, v.z), __fmul_rn(w1, v.y)),
                                    __fmul_rn(w2, v.x));
                float pred = fminf(fmaxf(d, MINV), MAXV);
                float res = __fsub_rn(v.w, pred);
                // sgmu = MU * sign(res)  (exact: MU is a power of two)
                float sg = res > 0.0f ? kMU() : (res < 0.0f ? -kMU() : 0.0f);
                // w += (MU*sign)*n, elementwise, separate rounded mul+add
                w0 = __fadd_rn(w0, __fmul_rn(sg, v.z));
                w1 = __fadd_rn(w1, __fmul_rn(sg, v.y));
                w2 = __fadd_rn(w2, __fmul_rn(sg, v.x));
                outp[(size_t)t * ZB] = pred;
            }
            // refill this slot with group g+PF (clamped; tail loads are redundant)
            int gl = g + PF;
            if (gl >= NG) gl = NG - 1;
#pragma unroll
            for (int j = 0; j < U; ++j)
                buf[s][j] = base[(size_t)(gl * U + j) * ZB];
        }
    }
}

// ---------------------------------------------------------------------------
// Phase C: elementwise outputs from predT + image. LDS-transposes a 64-pixel
// tile of predT so every global read/write is coalesced.
// Reads  d_out[4N,5N) (predT); writes d_out[0,4N) and [5N,6N). No overlap.
// ---------------------------------------------------------------------------
__global__ __launch_bounds__(256) void finalize_kernel(const float* __restrict__ img,
                                                       const float* __restrict__ predT,
                                                       float* __restrict__ out) {
    __shared__ float lds[64 * ZB];  // 51.7 KB
    const int t0 = blockIdx.x * 64;
    const float* src = predT + (size_t)t0 * ZB;
    for (int i = threadIdx.x; i < 64 * ZB; i += 256) lds[i] = src[i];
    __syncthreads();

    for (int k = 0; k < 51; ++k) {
        int e = k * 256 + threadIdx.x;
        if (e < 64 * ZB) {
            int zz = e >> 6;
            int tl = e & 63;
            float pred = lds[tl * ZB + zz];          // stride 202 -> 2-way bank alias (free)
            size_t o = (size_t)zz * YX + t0 + tl;
            float s = img[o];
            float res = __fsub_rn(s, pred);
            int q = (int)rintf(res);                  // round-half-even == jnp.round
            int m = (q >= 0) ? (2 * q) : (-2 * q - 1);
            out[o] = pred;                            // predictions
            out[NTOT + o] = res;                      // residuals
            out[2 * NTOT + o] = res;                  // quantized_residuals
            out[3 * NTOT + o] = (float)m;             // mapped_indices
            out[5 * NTOT + o] = __fadd_rn(pred, res); // reconstructed
        }
    }
}

// ---------------------------------------------------------------------------
// Phase D: sample_representatives = image (runs after finalize has read predT
// out of this region).
// ---------------------------------------------------------------------------
__global__ __launch_bounds__(256) void repr_kernel(const float4* __restrict__ img4,
                                                   float4* __restrict__ out4) {
    size_t n4 = NTOT / 4;
    for (size_t i = (size_t)blockIdx.x * blockDim.x + threadIdx.x; i < n4;
         i += (size_t)gridDim.x * blockDim.x)
        out4[i] = img4[i];
}

extern "C" void kernel_launch(void* const* d_in, const int* in_sizes, int n_in,
                              void* d_out, int out_size, void* d_ws, size_t ws_size,
                              hipStream_t stream) {
    const float* img = (const float*)d_in[0];
    const float* w0g = (const float*)d_in[1];
    float* out = (float*)d_out;

    // Scratch carved out of d_out (dead before the final writers touch it):
    //   tmp4  = d_out[0 .. 4N) floats  (exactly N float4s)
    //   predT = d_out[4N .. 5N) floats (later overwritten by repr_kernel)
    float4* tmp4 = (float4*)d_out;
    float* predT = out + 4 * NTOT;

    dim3 gA(YX / 64, 4);
    pack_kernel<<<gA, 256, 0, stream>>>(img, tmp4);
    scan_kernel<<<4, 64, 0, stream>>>(tmp4, w0g, predT);
    finalize_kernel<<<YX / 64, 256, 0, stream>>>(img, predT, out);
    repr_kernel<<<4096, 256, 0, stream>>>((const float4*)img, (float4*)(out + 4 * NTOT));
}

// Round 2
// 5454.339 us; speedup vs baseline: 1.0134x; 1.0134x over previous
//
#include <hip/hip_runtime.h>

#define ZB 202
#define YX 65536
#define NTOT ((size_t)ZB * YX)

__device__ __forceinline__ constexpr float kMU() { return 0.0009765625f; }  // 2^-10
#define MINV (-32768.0f)
#define MAXV (32767.0f)

// ---------------------------------------------------------------------------
// Phase A: pack tmp4[t][z] = {img[z-3], img[z-2], img[z-1], img[z]} at pixel t.
// LDS tile: 64 z x 64 t (+3 z halo). Reads coalesced along t, writes 1KB
// contiguous float4 runs along z.
// ---------------------------------------------------------------------------
__global__ __launch_bounds__(256) void pack_kernel(const float* __restrict__ img,
                                                   float4* __restrict__ tmp4) {
    __shared__ float lds[67 * 65];  // rows = img z0-3 .. z0+63, pitch 65 (bank-conflict pad)
    const int t0 = blockIdx.x * 64;
    const int z0 = blockIdx.y * 64;
    const int tid = threadIdx.x;
    const int c = tid & 63;
    const int r0 = tid >> 6;

    for (int k = 0; k < 17; ++k) {
        int r = r0 + (k << 2);
        if (r < 67) {
            int gz = z0 - 3 + r;
            float v = 0.0f;
            if (gz >= 0 && gz < ZB) v = img[(size_t)gz * YX + t0 + c];
            lds[r * 65 + c] = v;
        }
    }
    __syncthreads();

    const int zl = tid & 63;
    const int tsub = tid >> 6;
    const int z = z0 + zl;
    if (z >= ZB) return;
    for (int k = 0; k < 16; ++k) {
        int tl = tsub * 16 + k;
        float4 v;
        v.x = lds[(zl + 0) * 65 + tl];  // img[z-3] = n2
        v.y = lds[(zl + 1) * 65 + tl];  // img[z-2] = n1
        v.z = lds[(zl + 2) * 65 + tl];  // img[z-1] = n0
        v.w = lds[(zl + 3) * 65 + tl];  // img[z]   = s
        tmp4[(size_t)(t0 + tl) * ZB + z] = v;
    }
}

// ---------------------------------------------------------------------------
// Phase B: the sequential sign-LMS scan. One lane per band; 4 waves total,
// so occupancy is irrelevant -> __launch_bounds__(64,1) for a 512-VGPR budget
// (round 1's 112-VGPR cap spilled the 128-VGPR prefetch buffer to scratch:
// 187 cyc/step). 32 pixels in flight in registers (~1000 cyc latency cover).
//
// Recurrence kept bit-exact vs reference:
//  - d uses the same 3-mul + left-to-right 2-add order.
//  - sign(s - clip(d)) == sign(s - d) because |s| < 32767 always
//    (s ~ N(0,1000)); removes the clamp from the w-dependence chain.
//  - w' = fma(+-MU, v, w) is bit-identical to w + (MU*sign)*v: MU*v is an
//    exact power-of-two scale, so fma's single rounding == mul-then-add.
//  - stores UNCLIPPED d; finalize applies the clamp.
// Per step: 3 mul + 2 add + 2 cmp + 2 cndmask + 3 fma + 1 store ~= 14 instrs.
// ---------------------------------------------------------------------------
__global__ __launch_bounds__(64, 1) void scan_kernel(const float4* __restrict__ tmp4,
                                                     const float* __restrict__ w0g,
                                                     float* __restrict__ dT) {
    const int z = blockIdx.x * 64 + threadIdx.x;
    if (z >= ZB) return;

    float w0 = w0g[z * 3 + 0];
    float w1 = w0g[z * 3 + 1];
    float w2 = w0g[z * 3 + 2];

    const float4* base = tmp4 + z;
    float* outp = dT + z;

    constexpr int IF = 32;  // pixels in flight (128 VGPRs of buffer)
    float4 buf[IF];
#pragma unroll
    for (int i = 0; i < IF; ++i) buf[i] = base[(size_t)i * ZB];

    for (int T = 0; T < YX; T += IF) {
#pragma unroll
        for (int i = 0; i < IF; ++i) {
            const float4 v = buf[i];
            // d: identical op order to the validated round-1 kernel
            float d = __fadd_rn(__fadd_rn(__fmul_rn(w0, v.z), __fmul_rn(w1, v.y)),
                                __fmul_rn(w2, v.x));
            // sg = MU * sign(s - clip(d)) ; clip dropped from the chain (see above)
            float sg = (v.w > d) ? kMU() : ((v.w < d) ? -kMU() : 0.0f);
            w0 = __builtin_fmaf(sg, v.z, w0);
            w1 = __builtin_fmaf(sg, v.y, w1);
            w2 = __builtin_fmaf(sg, v.x, w2);
            outp[(size_t)(T + i) * ZB] = d;
            // prefetch pixel T+i+IF into this slot (tail loads clamp: redundant)
            int nt = T + i + IF;
            if (nt > YX - 1) nt = YX - 1;
            buf[i] = base[(size_t)nt * ZB];
        }
    }
}

// ---------------------------------------------------------------------------
// Phase C: elementwise outputs from dT + image. LDS-transposes a 64-pixel
// tile of dT so every global read/write is coalesced. Applies the clamp
// that scan deferred.
// Reads  d_out[4N,5N) (dT); writes d_out[0,4N) and [5N,6N). No overlap.
// ---------------------------------------------------------------------------
__global__ __launch_bounds__(256) void finalize_kernel(const float* __restrict__ img,
                                                       const float* __restrict__ dT,
                                                       float* __restrict__ out) {
    __shared__ float lds[64 * ZB];  // 51.7 KB
    const int t0 = blockIdx.x * 64;
    const float* src = dT + (size_t)t0 * ZB;
    for (int i = threadIdx.x; i < 64 * ZB; i += 256) lds[i] = src[i];
    __syncthreads();

    for (int k = 0; k < 51; ++k) {
        int e = k * 256 + threadIdx.x;
        if (e < 64 * ZB) {
            int zz = e >> 6;
            int tl = e & 63;
            float dv = lds[tl * ZB + zz];            // stride 202 -> 2-way bank alias (free)
            float pred = fminf(fmaxf(dv, MINV), MAXV);
            size_t o = (size_t)zz * YX + t0 + tl;
            float s = img[o];
            float res = __fsub_rn(s, pred);
            int q = (int)rintf(res);                  // round-half-even == jnp.round
            int m = (q >= 0) ? (2 * q) : (-2 * q - 1);
            out[o] = pred;                            // predictions
            out[NTOT + o] = res;                      // residuals
            out[2 * NTOT + o] = res;                  // quantized_residuals
            out[3 * NTOT + o] = (float)m;             // mapped_indices
            out[5 * NTOT + o] = __fadd_rn(pred, res); // reconstructed
        }
    }
}

// ---------------------------------------------------------------------------
// Phase D: sample_representatives = image (runs after finalize has read dT
// out of this region).
// ---------------------------------------------------------------------------
__global__ __launch_bounds__(256) void repr_kernel(const float4* __restrict__ img4,
                                                   float4* __restrict__ out4) {
    size_t n4 = NTOT / 4;
    for (size_t i = (size_t)blockIdx.x * blockDim.x + threadIdx.x; i < n4;
         i += (size_t)gridDim.x * blockDim.x)
        out4[i] = img4[i];
}

extern "C" void kernel_launch(void* const* d_in, const int* in_sizes, int n_in,
                              void* d_out, int out_size, void* d_ws, size_t ws_size,
                              hipStream_t stream) {
    const float* img = (const float*)d_in[0];
    const float* w0g = (const float*)d_in[1];
    float* out = (float*)d_out;

    // Scratch carved out of d_out (dead before the final writers touch it):
    //   tmp4 = d_out[0 .. 4N) floats  (exactly N float4s)
    //   dT   = d_out[4N .. 5N) floats (later overwritten by repr_kernel)
    float4* tmp4 = (float4*)d_out;
    float* dT = out + 4 * NTOT;

    dim3 gA(YX / 64, 4);
    pack_kernel<<<gA, 256, 0, stream>>>(img, tmp4);
    scan_kernel<<<4, 64, 0, stream>>>(tmp4, w0g, dT);
    finalize_kernel<<<YX / 64, 256, 0, stream>>>(img, dT, out);
    repr_kernel<<<4096, 256, 0, stream>>>((const float4*)img, (float4*)(out + 4 * NTOT));
}